// Round 4
// baseline (215.332 us; speedup 1.0000x reference)
//
#include <hip/hip_runtime.h>
#include <math.h>

// Probabilistic Slot Attention, B=8 N=4096 K=8 D=256, 3 iterations.
// Round 6: k_prep (64 blocks, 25% CU) replaced by k_red (512 blocks, full
// occupancy). Block = (bk, ds) owns a 32-d slice: weighted chunk reduce
// (normalized weights aS=wc/S folded in), w_ws/slots_out slice writes,
// cst log-sum via one atomicAdd per block into cst_acc[it][bk]; next
// k_fuse reads cst = LOGNORM - 0.5*acc. attn written in 512-n slices.
// k_setup zeroes cst_acc. k_fuse/k_gemm/k_setup otherwise unchanged.

#define Bd 8
#define Nd 4096
#define Kd 8
#define Dd 256
#define Md (Bd*Nd)              // 32768 rows
#define NITER 3
#define EPSf 1e-8f
#define LNEPS 1e-5f
#define NCH 64                  // n-chunks per (b): 64 chunks x 64 n
#define LOGNORM -235.24826450039617f   // -0.5*256*log(2*pi)

typedef float f32x4 __attribute__((ext_vector_type(4)));
typedef short bf16x8 __attribute__((ext_vector_type(8)));
typedef unsigned short ushort_t;
typedef unsigned short us4 __attribute__((ext_vector_type(4)));

// workspace float offsets
#define KEYS_OFF 0
#define VALS_OFF (Md*Dd)
#define E_OFF    (2*Md*Dd)                 // unnormalized exp(g - m_chunk), (B,K,N)
#define Q_OFF    (E_OFF + Bd*Kd*Nd)
#define W_OFF    (Q_OFF + Bd*Kd*Dd)
#define CST_OFF  (W_OFF + Bd*Kd*Dd)
#define CSTA_OFF (CST_OFF + 64)            // cst_acc[3][64] log-sum accumulators
#define MSP_OFF  (CSTA_OFF + 192)          // chunk max, (B*K, NCH)
#define SSP_OFF  (MSP_OFF + Bd*Kd*NCH)     // chunk expsum
#define PMU_OFF  (SSP_OFF + Bd*Kd*NCH)     // (B, NCH, K, D) partial mu (unnorm)
#define PS2_OFF  (PMU_OFF + Bd*NCH*Kd*Dd)  // partial E[v^2] (unnorm)
#define WH_OFF   (PS2_OFF + Bd*NCH*Kd*Dd)  // ushort[512*256] == 65536 floats
#define WL_OFF   (WH_OFF + 65536)
#define XH_OFF   (WL_OFF + 65536)
#define XL_OFF   (XH_OFF + Md*Dd/2)
#define WS_TOTAL (XL_OFF + Md*Dd/2)

__device__ __forceinline__ ushort_t f2bf(float f) {
    unsigned u = __float_as_uint(f);
    return (ushort_t)((u + 0x7FFFu + ((u >> 16) & 1u)) >> 16);   // RNE
}
__device__ __forceinline__ float b2f(ushort_t h) {
    return __uint_as_float(((unsigned)h) << 16);
}
__device__ __forceinline__ void gload_lds16(const void* g, void* l) {
    __builtin_amdgcn_global_load_lds(
        (__attribute__((address_space(1))) void*)g,
        (__attribute__((address_space(3))) void*)l, 16, 0, 0);
}

// ---------------------------------------------------------------------------
// Setup: blocks [0,1024) LN+bf16-split of emb; [1024,1536) W split;
// [1536,1600) slot init (queries, w, cst, zero cst_acc).
__global__ __launch_bounds__(256) void k_setup(
        const float* __restrict__ emb, const float* __restrict__ lns,
        const float* __restrict__ lnb, const float* __restrict__ Wk,
        const float* __restrict__ Wv, const float* __restrict__ mu0,
        const float* __restrict__ lsig, const float* __restrict__ nz0,
        const float* __restrict__ Wq, ushort_t* __restrict__ xh,
        ushort_t* __restrict__ xl, ushort_t* __restrict__ Wh,
        ushort_t* __restrict__ Wl, float* __restrict__ qout,
        float* __restrict__ w_ws, float* __restrict__ cst_ws,
        float* __restrict__ cst_acc) {
    __shared__ float s_s[256];
    __shared__ float red[256];
    const int bx = blockIdx.x;
    if (bx < 1024) {
        // ---- LN + hi/lo bf16 split ----
        const int tid = threadIdx.x, wave = tid >> 6, lane = tid & 63;
        const int row0 = bx * 32;
        const float4 sc = ((const float4*)lns)[lane];
        const float4 bi = ((const float4*)lnb)[lane];
        for (int rr = 0; rr < 8; ++rr) {
            const int r = row0 + wave * 8 + rr;
            const float4 e4 = ((const float4*)(emb + (size_t)r * Dd))[lane];
            float s = e4.x + e4.y + e4.z + e4.w;
            #pragma unroll
            for (int off = 32; off; off >>= 1) s += __shfl_xor(s, off);
            const float m = s * (1.0f / 256.0f);
            const float dx = e4.x - m, dy = e4.y - m, dz = e4.z - m, dw = e4.w - m;
            float ss = dx * dx + dy * dy + dz * dz + dw * dw;
            #pragma unroll
            for (int off = 32; off; off >>= 1) ss += __shfl_xor(ss, off);
            const float rs = 1.0f / sqrtf(ss * (1.0f / 256.0f) + LNEPS);
            float x[4];
            x[0] = dx * rs * sc.x + bi.x;
            x[1] = dy * rs * sc.y + bi.y;
            x[2] = dz * rs * sc.z + bi.z;
            x[3] = dw * rs * sc.w + bi.w;
            us4 h4, l4;
            #pragma unroll
            for (int j = 0; j < 4; ++j) {
                const ushort_t h = f2bf(x[j]);
                h4[j] = h;
                l4[j] = f2bf(x[j] - b2f(h));
            }
            *(us4*)(xh + (size_t)r * Dd + lane * 4) = h4;
            *(us4*)(xl + (size_t)r * Dd + lane * 4) = l4;
        }
    } else if (bx < 1536) {
        // ---- W split ----
        const int r = bx - 1024, d = threadIdx.x;
        const float w = (r < 256) ? Wk[(size_t)r * 256 + d]
                                  : Wv[(size_t)(r - 256) * 256 + d];
        const ushort_t h = f2bf(w);
        Wh[(size_t)r * 256 + d] = h;
        Wl[(size_t)r * 256 + d] = f2bf(w - b2f(h));
    } else {
        // ---- init: q = slots @ Wq^T, iteration-0 w & cst ----
        const int bk = bx - 1536;
        const int k = bk & 7;
        const int d = threadIdx.x;
        if (d < 3) cst_acc[d * 64 + bk] = 0.0f;
        const float sg = expf(lsig[k * 256 + d]);
        s_s[d] = mu0[k * 256 + d] + sg * nz0[(size_t)bk * 256 + d];
        w_ws[(size_t)bk * 256 + d] = 1.0f / (sg * sg + EPSf);
        red[d] = logf(fabsf(sg) + EPSf);
        __syncthreads();
        for (int s = 128; s; s >>= 1) {
            if (d < s) red[d] += red[d + s];
            __syncthreads();
        }
        if (d == 0) cst_ws[bk] = LOGNORM - 0.5f * red[0];
        float acc = 0.0f;
        const float4* Wr = (const float4*)(Wq + (size_t)d * 256);
        const float4* sp = (const float4*)s_s;
        #pragma unroll 8
        for (int j = 0; j < 64; ++j) {
            const float4 w4 = Wr[j], s4 = sp[j];
            acc += w4.x * s4.x + w4.y * s4.y + w4.z * s4.z + w4.w * s4.w;
        }
        qout[(size_t)bk * 256 + d] = acc;
    }
}

// ---------------------------------------------------------------------------
// GEMM: C[32768 x 512] = x x [Wk||Wv]^T via split-bf16 MFMA (unchanged).
__global__ __launch_bounds__(256, 2) void k_gemm(
        const ushort_t* __restrict__ xh, const ushort_t* __restrict__ xl,
        const ushort_t* __restrict__ Wh, const ushort_t* __restrict__ Wl,
        float* __restrict__ keys, float* __restrict__ vals) {
    __shared__ ushort_t Ah[128 * 32], Al[128 * 32];   // 8 KB each
    __shared__ ushort_t Bh[256 * 32], Bl[256 * 32];   // 16 KB each
    const int tid = threadIdx.x, lane = tid & 63, wave = tid >> 6;
    const int row0 = blockIdx.x * 128;
    const int cb = blockIdx.y;                 // 0 -> keys, 1 -> vals
    const int wm = wave >> 1, wn = wave & 1;

    f32x4 acc[4][8];
    #pragma unroll
    for (int a = 0; a < 4; ++a)
        #pragma unroll
        for (int b = 0; b < 8; ++b) acc[a][b] = (f32x4)(0.0f);

    for (int jb = 0; jb < 256; jb += 32) {
        #pragma unroll
        for (int i = 0; i < 2; ++i) {
            const int p = tid + i * 256;
            const int r = p >> 2, gp = p & 3;
            const int g = gp ^ ((r >> 1) & 3);
            const size_t goff = (size_t)(row0 + r) * 256 + jb + g * 8;
            gload_lds16(xh + goff, &Ah[p * 8]);
            gload_lds16(xl + goff, &Al[p * 8]);
        }
        #pragma unroll
        for (int i = 0; i < 4; ++i) {
            const int p = (wave * 4 + i) * 64 + lane;
            const int r = p >> 2, gp = p & 3;
            const int g = gp ^ ((r >> 1) & 3);
            const size_t goff = (size_t)(cb * 256 + r) * 256 + jb + g * 8;
            gload_lds16(Wh + goff, &Bh[p * 8]);
            gload_lds16(Wl + goff, &Bl[p * 8]);
        }
        __syncthreads();

        bf16x8 bhf[8], blf[8];
        #pragma unroll
        for (int ni = 0; ni < 8; ++ni) {
            const int c = wn * 128 + ni * 16 + (lane & 15);
            const int g = lane >> 4;
            const int off = c * 32 + ((g ^ ((c >> 1) & 3)) << 3);
            bhf[ni] = *(const bf16x8*)&Bh[off];
            blf[ni] = *(const bf16x8*)&Bl[off];
        }
        #pragma unroll
        for (int mi = 0; mi < 4; ++mi) {
            const int rr = wm * 64 + mi * 16 + (lane & 15);
            const int g = lane >> 4;
            const int off = rr * 32 + ((g ^ ((rr >> 1) & 3)) << 3);
            const bf16x8 ah = *(const bf16x8*)&Ah[off];
            const bf16x8 al = *(const bf16x8*)&Al[off];
            #pragma unroll
            for (int ni = 0; ni < 8; ++ni) {
                acc[mi][ni] = __builtin_amdgcn_mfma_f32_16x16x32_bf16(ah, bhf[ni], acc[mi][ni], 0, 0, 0);
                acc[mi][ni] = __builtin_amdgcn_mfma_f32_16x16x32_bf16(ah, blf[ni], acc[mi][ni], 0, 0, 0);
                acc[mi][ni] = __builtin_amdgcn_mfma_f32_16x16x32_bf16(al, bhf[ni], acc[mi][ni], 0, 0, 0);
            }
        }
        __syncthreads();
    }
    float* outp = (cb == 0) ? keys : vals;
    #pragma unroll
    for (int mi = 0; mi < 4; ++mi) {
        const int rbase = row0 + wm * 64 + mi * 16 + ((lane >> 4) << 2);
        #pragma unroll
        for (int ni = 0; ni < 8; ++ni) {
            const int col = wn * 128 + ni * 16 + (lane & 15);
            #pragma unroll
            for (int rg = 0; rg < 4; ++rg)
                outp[(size_t)(rbase + rg) * Dd + col] = acc[mi][ni][rg];
        }
    }
}

// ---------------------------------------------------------------------------
// Fused gll + chunk-softmax + partial mu/s2 (structure as round 5).
// cst read: it==0 from cst_ws, else LOGNORM - 0.5*cst_acc[it-1][bk].
__global__ __launch_bounds__(512, 4) void k_fuse(
        const float* __restrict__ keys, const float* __restrict__ vals,
        const float* __restrict__ q_ws, const float* __restrict__ w_ws,
        const float* __restrict__ cst_ws, const float* __restrict__ cst_acc,
        float* __restrict__ e_glob, float* __restrict__ msp,
        float* __restrict__ ssp, float* __restrict__ pmu,
        float* __restrict__ ps2, const int it, const int last) {
    __shared__ float buf[16384];        // 64 KB: keys chunk, then vals chunk
    __shared__ float e_s[8][64];        // 2 KB
    const int tid = threadIdx.x, lane = tid & 63, wv = tid >> 6;
    const int b = blockIdx.x >> 6, chunk = blockIdx.x & 63;
    const int n0 = chunk * 64;
    const int wvu = __builtin_amdgcn_readfirstlane(wv);

    // ---- stage keys: granule g' of row r holds logical granule g'^r ----
    const float* kbase = keys + ((size_t)b * Nd + n0) * Dd;
    #pragma unroll
    for (int i = 0; i < 8; ++i) {
        const int p = i * 512 + tid;            // granule 0..4095
        const int row = p >> 6, gp = p & 63;
        const int g = gp ^ row;
        gload_lds16(kbase + (size_t)row * Dd + g * 4, &buf[p * 4]);
    }
    __syncthreads();

    // ---- phase A: wave wv = slot k; lane = n ----
    const int bkf = b * Kd + wvu;
    const float4* qk = (const float4*)(q_ws + (size_t)bkf * Dd);
    const float4* wk = (const float4*)(w_ws + (size_t)bkf * Dd);
    const float cstv = (it == 0) ? cst_ws[bkf]
                     : fmaf(-0.5f, cst_acc[(it - 1) * 64 + bkf], LOGNORM);
    const float* krow = &buf[lane * 256];
    float ax = 0.f, ay = 0.f, az = 0.f, aw = 0.f;
    #pragma unroll 8
    for (int g = 0; g < 64; ++g) {
        const float4 k4 = *(const float4*)&krow[(g ^ lane) * 4];
        const float4 q4 = qk[g];
        const float4 w4 = wk[g];
        float t;
        t = k4.x - q4.x; ax += t * t * w4.x;
        t = k4.y - q4.y; ay += t * t * w4.y;
        t = k4.z - q4.z; az += t * t * w4.z;
        t = k4.w - q4.w; aw += t * t * w4.w;
    }
    float gv = cstv - 0.5f * ((ax + ay) + (az + aw));
    gv = fminf(fmaxf(gv, -10000.0f), 10000.0f);
    float m = gv;
    #pragma unroll
    for (int off = 32; off; off >>= 1) m = fmaxf(m, __shfl_xor(m, off));
    const float e = expf(gv - m);
    float ssum = e;
    #pragma unroll
    for (int off = 32; off; off >>= 1) ssum += __shfl_xor(ssum, off);
    e_s[wv][lane] = e;
    if (last) e_glob[((size_t)bkf) * Nd + n0 + lane] = e;
    if (lane == 0) {
        msp[bkf * NCH + chunk] = m;
        ssp[bkf * NCH + chunk] = ssum;
    }
    __syncthreads();

    // ---- stage vals (linear) ----
    const float* vbase = vals + ((size_t)b * Nd + n0) * Dd;
    #pragma unroll
    for (int i = 0; i < 8; ++i) {
        const int p = i * 512 + tid;
        gload_lds16(vbase + (size_t)p * 4, &buf[p * 4]);
    }
    __syncthreads();

    // ---- phase B: wave wv accumulates k=wv over the chunk from LDS ----
    float4 mu4 = {0.f, 0.f, 0.f, 0.f}, s24 = {0.f, 0.f, 0.f, 0.f};
    #pragma unroll 8
    for (int n = 0; n < 64; ++n) {
        const float4 v = *(const float4*)&buf[n * 256 + lane * 4];
        const float a = e_s[wv][n];
        mu4.x += a * v.x; mu4.y += a * v.y; mu4.z += a * v.z; mu4.w += a * v.w;
        s24.x += a * v.x * v.x; s24.y += a * v.y * v.y;
        s24.z += a * v.z * v.z; s24.w += a * v.w * v.w;
    }
    const size_t o = (((size_t)(b * NCH + chunk)) * Kd + wv) * Dd + lane * 4;
    *(float4*)(pmu + o) = mu4;
    *(float4*)(ps2 + o) = s24;
}

// ---------------------------------------------------------------------------
// Reduce: 512 blocks = (bk, ds). Block owns d-slice [ds*32, ds*32+32):
// normalized chunk weights aS = exp(m_c-M)*s_c-normalized (wave 0), weighted
// chunk-reduce of pmu/ps2 (thread = chunk x float4, shfl+LDS tree), then
// sigma/w_ws/slots_out for the slice and one atomicAdd of the partial
// log-sum into cst_acc[it][bk]. Last iter: attn 512-n slice.
__global__ __launch_bounds__(512) void k_red(
        const float* __restrict__ msp, const float* __restrict__ ssp,
        const float* __restrict__ pmu, const float* __restrict__ ps2,
        float* __restrict__ w_ws, float* __restrict__ cst_acc,
        const float* __restrict__ nzf, float* __restrict__ slots_out,
        const float* __restrict__ e_glob, float* __restrict__ attn,
        const int it, const int last) {
    __shared__ float aS[64];
    __shared__ f32x4 redm[8][8], red2[8][8];
    const int bx = blockIdx.x;
    const int bk = bx >> 3, ds = bx & 7;
    const int b = bk >> 3, k = bk & 7;
    const int tid = threadIdx.x, lane = tid & 63, wv = tid >> 6;

    if (wv == 0) {
        const float m_c = msp[bk * NCH + lane];
        const float s_c = ssp[bk * NCH + lane];
        float M = m_c;
        #pragma unroll
        for (int off = 32; off; off >>= 1) M = fmaxf(M, __shfl_xor(M, off));
        const float wc = expf(m_c - M);
        float S = wc * s_c;
        #pragma unroll
        for (int off = 32; off; off >>= 1) S += __shfl_xor(S, off);
        aS[lane] = wc / S;
    }
    __syncthreads();

    // thread = (chunk c0 = tid>>3, float4 f = tid&7) of the 32-d slice
    const int c0 = tid >> 3, f = tid & 7;
    const size_t base = (((size_t)(b * NCH + c0)) * Kd + k) * Dd + ds * 32 + f * 4;
    const float a = aS[c0];
    const float4 pm = *(const float4*)(pmu + base);
    const float4 p2 = *(const float4*)(ps2 + base);
    f32x4 m4 = {a * pm.x, a * pm.y, a * pm.z, a * pm.w};
    f32x4 e4 = {a * p2.x, a * p2.y, a * p2.z, a * p2.w};
    #pragma unroll
    for (int off = 8; off < 64; off <<= 1) {
        m4.x += __shfl_xor(m4.x, off); m4.y += __shfl_xor(m4.y, off);
        m4.z += __shfl_xor(m4.z, off); m4.w += __shfl_xor(m4.w, off);
        e4.x += __shfl_xor(e4.x, off); e4.y += __shfl_xor(e4.y, off);
        e4.z += __shfl_xor(e4.z, off); e4.w += __shfl_xor(e4.w, off);
    }
    if (lane < 8) { redm[wv][lane] = m4; red2[wv][lane] = e4; }
    __syncthreads();

    if (wv == 0) {
        f32x4 mm = redm[lane >> 3][lane & 7];
        f32x4 ee = red2[lane >> 3][lane & 7];
        #pragma unroll
        for (int off = 8; off < 64; off <<= 1) {
            mm.x += __shfl_xor(mm.x, off); mm.y += __shfl_xor(mm.y, off);
            mm.z += __shfl_xor(mm.z, off); mm.w += __shfl_xor(mm.w, off);
            ee.x += __shfl_xor(ee.x, off); ee.y += __shfl_xor(ee.y, off);
            ee.z += __shfl_xor(ee.z, off); ee.w += __shfl_xor(ee.w, off);
        }
        if (lane < 8) {
            const int d0 = ds * 32 + lane * 4;
            const float sgx = ee.x - mm.x * mm.x;
            const float sgy = ee.y - mm.y * mm.y;
            const float sgz = ee.z - mm.z * mm.z;
            const float sgw = ee.w - mm.w * mm.w;
            float4 wout;
            wout.x = 1.0f / (sgx * sgx + EPSf);
            wout.y = 1.0f / (sgy * sgy + EPSf);
            wout.z = 1.0f / (sgz * sgz + EPSf);
            wout.w = 1.0f / (sgw * sgw + EPSf);
            *(float4*)(w_ws + (size_t)bk * Dd + d0) = wout;
            if (last) {
                const float4 nz = *(const float4*)(nzf + (size_t)bk * Dd + d0);
                float4 so;
                so.x = mm.x + fmaxf(fabsf(sgx), EPSf) * nz.x;
                so.y = mm.y + fmaxf(fabsf(sgy), EPSf) * nz.y;
                so.z = mm.z + fmaxf(fabsf(sgz), EPSf) * nz.z;
                so.w = mm.w + fmaxf(fabsf(sgw), EPSf) * nz.w;
                *(float4*)(slots_out + (size_t)bk * Dd + d0) = so;
            }
            float ls = logf(fabsf(sgx) + EPSf) + logf(fabsf(sgy) + EPSf)
                     + logf(fabsf(sgz) + EPSf) + logf(fabsf(sgw) + EPSf);
            #pragma unroll
            for (int off = 1; off < 8; off <<= 1) ls += __shfl_xor(ls, off);
            if (lane == 0) atomicAdd(cst_acc + it * 64 + bk, ls);
        }
    }
    if (last && tid < 128) {
        const int idx = ds * 128 + tid;          // float4 index into 4096-row
        const float4 ev = ((const float4*)(e_glob + (size_t)bk * Nd))[idx];
        const float s = aS[idx >> 4];            // chunk = (idx*4)>>6
        float4 o4;
        o4.x = ev.x * s; o4.y = ev.y * s; o4.z = ev.z * s; o4.w = ev.w * s;
        ((float4*)(attn + (size_t)bk * Nd))[idx] = o4;
    }
}

// ---------------------------------------------------------------------------
extern "C" void kernel_launch(void* const* d_in, const int* in_sizes, int n_in,
                              void* d_out, int out_size, void* d_ws, size_t ws_size,
                              hipStream_t stream) {
    const float* emb  = (const float*)d_in[0];
    const float* mu0  = (const float*)d_in[1];
    const float* lsig = (const float*)d_in[2];
    // d_in[3] mixing_coeffs: cancels in softmax over N.
    const float* Wq   = (const float*)d_in[4];
    const float* Wk   = (const float*)d_in[5];
    const float* Wv   = (const float*)d_in[6];
    const float* lns  = (const float*)d_in[7];
    const float* lnb  = (const float*)d_in[8];
    const float* nz0  = (const float*)d_in[9];
    const float* nzf  = (const float*)d_in[10];
    // d_in[11] num_iterations == 3.

    float* ws    = (float*)d_ws;
    float* out   = (float*)d_out;
    float* keys  = ws + KEYS_OFF;
    float* vals  = ws + VALS_OFF;
    float* eglob = ws + E_OFF;
    float* qws   = ws + Q_OFF;
    float* wws   = ws + W_OFF;
    float* cstw  = ws + CST_OFF;
    float* csta  = ws + CSTA_OFF;
    float* msp   = ws + MSP_OFF;
    float* ssp   = ws + SSP_OFF;
    float* pmu   = ws + PMU_OFF;
    float* ps2   = ws + PS2_OFF;
    ushort_t* Whp = (ushort_t*)(ws + WH_OFF);
    ushort_t* Wlp = (ushort_t*)(ws + WL_OFF);
    ushort_t* xhp = (ushort_t*)(ws + XH_OFF);
    ushort_t* xlp = (ushort_t*)(ws + XL_OFF);
    float* attn = out + Bd * Kd * Dd;   // (B,K,N) region of d_out

    k_setup<<<1600, 256, 0, stream>>>(emb, lns, lnb, Wk, Wv, mu0, lsig, nz0,
                                      Wq, xhp, xlp, Whp, Wlp, qws, wws, cstw,
                                      csta);
    k_gemm<<<dim3(256, 2), 256, 0, stream>>>(xhp, xlp, Whp, Wlp, keys, vals);
    for (int it = 0; it < NITER; ++it) {
        const int last = (it == NITER - 1);
        k_fuse<<<512, 512, 0, stream>>>(keys, vals, qws, wws, cstw, csta,
                                        eglob, msp, ssp, pmu, ps2, it, last);
        k_red<<<512, 512, 0, stream>>>(msp, ssp, pmu, ps2, wws, csta, nzf,
                                       out, eglob, attn, it, last);
    }
    (void)in_sizes; (void)n_in; (void)out_size; (void)ws_size;
}